// Round 8
// baseline (829.619 us; speedup 1.0000x reference)
//
#include <hip/hip_runtime.h>
#include <hip/hip_cooperative_groups.h>

namespace cg = cooperative_groups;

#define DD 128
#define SCAN_TILE 1024   // elements per scan tile (256 threads x 4)
#define HS 136           // padded hbuf stride (floats): clean 2-way banks
#define FR 16            // rows per fused block (16 -> 16.4 KB LDS -> 8 blk/CU)
#define PREP_GRID 1024   // cooperative grid: 4 blocks/CU guaranteed resident

typedef __attribute__((ext_vector_type(8))) short short8;
typedef __attribute__((ext_vector_type(4))) float f32x4;
typedef __attribute__((ext_vector_type(2))) float f32x2;

// bf16 round-to-nearest-even split helpers
__device__ inline unsigned short f2bf_rne(float f) {
    unsigned int u = __float_as_uint(f);
    unsigned int r = u + 0x7FFFu + ((u >> 16) & 1u);
    return (unsigned short)(r >> 16);
}
__device__ inline float bf2f(unsigned short h) {
    return __uint_as_float(((unsigned int)h) << 16);
}
// split (a,b) into packed bf16 hi pair + lo pair (residual)
__device__ inline void split2(float a, float b, unsigned int& hi, unsigned int& lo) {
    unsigned short ha = f2bf_rne(a), hb = f2bf_rne(b);
    float la = a - bf2f(ha), lb = b - bf2f(hb);
    hi = (unsigned int)ha | ((unsigned int)hb << 16);
    lo = (unsigned int)f2bf_rne(la) | ((unsigned int)f2bf_rne(lb) << 16);
}

// ---------------- Cooperative preamble: one kernel, 5 phases ----------------
// Phase 0: zero cur arrays + wprep (W split into MFMA B-frag planes)
// Phase 1: count edge destinations (atomics)
// Phase 2: per-tile degree sums -> bsum
// Phase 3: every block scans bsum in LDS; per-tile local exclusive scan
//          writes rowptr + cursor; block 0 writes totals
// Phase 4: fill dst-grouped packed (src,norm) records
__global__ __launch_bounds__(256, 4) void prep_kernel(
    const int* __restrict__ eud, const int* __restrict__ eus,
    const float* __restrict__ norm1, int E1,
    const int* __restrict__ eid, const int* __restrict__ eis,
    const float* __restrict__ norm2, int E2,
    int* cur_i, int* cur_u, int* row_i, int* row_u,
    int2* esn1, int2* esn2, int* bsum,
    int nb0, int nb1, int NI, int NU,
    const float* __restrict__ W1, const float* __restrict__ W2,
    unsigned short* wfrag)
{
    cg::grid_group grid = cg::this_grid();
    __shared__ int red[256];
    __shared__ int bs[512];
    __shared__ int ps[256];
    __shared__ int sh[256];

    int b   = blockIdx.x;
    int t   = threadIdx.x;
    int nB  = gridDim.x;
    int gid = b * 256 + t;
    int gsz = nB * 256;

    // ---- Phase 0: zero cursors (cur_i/cur_u contiguous) + wprep ----
    for (int i = gid; i < NI + NU; i += gsz) cur_i[i] = 0;
    if (b < 16) {
        int tt = b * 256 + t;              // 4096 threads
        int lane = tt & 63;
        int cf   = (tt >> 6) & 7;
        int ksm  = (tt >> 9) & 3;
        int mat  = tt >> 11;
        const float* W = mat ? W2 : W1;
        int g = lane >> 4, c = lane & 15;
        int n = cf * 16 + c;
        unsigned int hi[4], lo[4];
        #pragma unroll
        for (int p = 0; p < 4; ++p) {
            int k0 = ksm * 32 + g * 8 + p * 2;
            float v0 = W[(size_t)k0 * DD + n];
            float v1 = W[(size_t)(k0 + 1) * DD + n];
            split2(v0, v1, hi[p], lo[p]);
        }
        unsigned short* dh = wfrag + (size_t)mat * 32768
                           + ((size_t)(ksm * 8 + cf) * 64 + lane) * 8;
        unsigned short* dl = dh + 16384;
        *(uint4*)dh = make_uint4(hi[0], hi[1], hi[2], hi[3]);
        *(uint4*)dl = make_uint4(lo[0], lo[1], lo[2], lo[3]);
    }
    grid.sync();

    // ---- Phase 1: count ----
    for (int i = gid; i < E1 + E2; i += gsz) {
        if (i < E1) atomicAdd(cur_i + eud[i], 1);
        else        atomicAdd(cur_u + eid[i - E1], 1);
    }
    grid.sync();

    // ---- Phase 2: tile sums -> bsum ----
    int ntiles = nb0 + nb1;
    for (int tile = b; tile < ntiles; tile += nB) {
        const int* cur; int N, base;
        if (tile < nb0) { cur = cur_i; N = NI; base = tile * SCAN_TILE; }
        else            { cur = cur_u; N = NU; base = (tile - nb0) * SCAN_TILE; }
        int idx0 = base + t * 4;
        int s = 0;
        #pragma unroll
        for (int k = 0; k < 4; ++k) {
            int idx = idx0 + k;
            if (idx < N) s += cur[idx];
        }
        red[t] = s;
        __syncthreads();
        for (int o = 128; o >= 1; o >>= 1) {
            if (t < o) red[t] += red[t + o];
            __syncthreads();
        }
        if (t == 0) bsum[tile] = red[0];
        __syncthreads();
    }
    grid.sync();

    // ---- Phase 3: scan bsum in LDS (all blocks), then per-tile scan ----
    bs[t]       = (t < ntiles)       ? bsum[t]       : 0;
    bs[256 + t] = (256 + t < ntiles) ? bsum[256 + t] : 0;
    __syncthreads();
    int b0v = bs[2 * t], b1v = bs[2 * t + 1];
    int pair = b0v + b1v;
    ps[t] = pair;
    __syncthreads();
    for (int o = 1; o < 256; o <<= 1) {
        int u = (t >= o) ? ps[t - o] : 0;
        __syncthreads();
        ps[t] += u;
        __syncthreads();
    }
    int e0 = ps[t] - pair;              // exclusive prefix at element 2t
    __syncthreads();
    bs[2 * t]     = e0;
    bs[2 * t + 1] = e0 + b0v;
    __syncthreads();
    int grand = ps[255];
    int totI  = bs[nb0];                // total of item segment
    if (b == 0 && t == 0) {
        row_i[NI] = totI;
        row_u[NU] = grand - totI;
    }
    for (int tile = b; tile < ntiles; tile += nB) {
        int off = (tile < nb0) ? bs[tile] : bs[tile] - totI;
        int* cur; int* row;
        int N, base;
        if (tile < nb0) { cur = cur_i; row = row_i; N = NI; base = tile * SCAN_TILE; }
        else            { cur = cur_u; row = row_u; N = NU; base = (tile - nb0) * SCAN_TILE; }
        int idx0 = base + t * 4;
        int v[4];
        int s = 0;
        #pragma unroll
        for (int k = 0; k < 4; ++k) {
            int idx = idx0 + k;
            v[k] = (idx < N) ? cur[idx] : 0;
            s += v[k];
        }
        sh[t] = s;
        __syncthreads();
        for (int o = 1; o < 256; o <<= 1) {
            int u = (t >= o) ? sh[t - o] : 0;
            __syncthreads();
            sh[t] += u;
            __syncthreads();
        }
        int run = off + sh[t] - s;
        #pragma unroll
        for (int k = 0; k < 4; ++k) {
            int idx = idx0 + k;
            if (idx < N) {
                row[idx] = run;
                cur[idx] = run;
                run += v[k];
            }
        }
        __syncthreads();
    }
    grid.sync();

    // ---- Phase 4: fill packed (src, norm), dst-grouped ----
    for (int i = gid; i < E1 + E2; i += gsz) {
        if (i < E1) {
            int pos = atomicAdd(cur_i + eud[i], 1);
            esn1[pos] = make_int2(eus[i], __float_as_int(norm1[i]));
        } else {
            int e = i - E1;
            int pos = atomicAdd(cur_u + eid[e], 1);
            esn2[pos] = make_int2(eis[e], __float_as_int(norm2[e]));
        }
    }
}

// ---------------- Fallback: atomic scatter ----------------

__global__ __launch_bounds__(256) void scatter_kernel(
    const float* __restrict__ feat_src,
    const int* __restrict__ src,
    const int* __restrict__ dst,
    const float* __restrict__ norm,
    float* agg,
    float* ssum,
    int E)
{
    int gw = (int)((blockIdx.x * 256u + threadIdx.x) >> 6);
    int lane = threadIdx.x & 63;
    if (gw >= E) return;
    int si = src[gw];
    int di = dst[gw];
    float nv = norm[gw];
    float2 v = *(const float2*)(feat_src + (size_t)si * DD + lane * 2);
    float* ap = agg + (size_t)di * DD + lane * 2;
    unsafeAtomicAdd(ap,     v.x * nv);
    unsafeAtomicAdd(ap + 1, v.y * nv);
    if (lane == 0) unsafeAtomicAdd(ssum + di, nv);
}

// ---------------- Fused gather + MFMA finish (16 rows/block) ----------------
// Identical to R7's proven 149 us kernel.
__global__ __launch_bounds__(256, 8) void fused_kernel(
    const float* __restrict__ feat_user, const float* __restrict__ feat_item,
    const int* __restrict__ row_u, const int2* __restrict__ esnU,
    int NU, int nbU,
    const int* __restrict__ row_i, const int2* __restrict__ esnI, int NI,
    const unsigned short* __restrict__ wfrag,
    const float* __restrict__ b1, const float* __restrict__ b2,
    float* out_base)
{
    __shared__ __align__(16) char smem[FR * 512 * 2];   // 16 KB: Ah | Al
    __shared__ float sst[FR];

    const float *featO, *featS;
    const int *row;
    const int2 *esn;
    float* out;
    int row0, nrows;
    if ((int)blockIdx.x < nbU) {
        featO = feat_user; featS = feat_item; row = row_u; esn = esnU;
        out = out_base; row0 = blockIdx.x * FR; nrows = NU;
    } else {
        featO = feat_item; featS = feat_user; row = row_i; esn = esnI;
        out = out_base + (size_t)NU * DD;
        row0 = (blockIdx.x - nbU) * FR; nrows = NI;
    }

    int t = threadIdx.x;
    int w = t >> 6;
    int lane = t & 63;
    char* pAh = smem;
    char* pAl = smem + FR * 512;

    // ---- Phase G: gather + stage (4 rows per wave, 6-deep load pipe) ----
    for (int rr = 0; rr < 4; ++rr) {
        int r = w * 4 + rr;
        int grow = row0 + r;
        float2 acc = {0.f, 0.f};
        float sn = 0.f;
        f32x2 f2 = {0.f, 0.f};
        if (grow < nrows) {
            f2 = __builtin_nontemporal_load(
                     (const f32x2*)(featO + (size_t)grow * DD + lane * 2));
            int beg = row[grow], end = row[grow + 1];
            int j = beg;
            for (; j + 6 <= end; j += 6) {       // 6 source rows in flight
                int2 e0 = esn[j],     e1 = esn[j + 1], e2 = esn[j + 2];
                int2 e3 = esn[j + 3], e4 = esn[j + 4], e5 = esn[j + 5];
                const float* fb = featS + lane * 2;
                float2 v0 = *(const float2*)(fb + ((size_t)e0.x << 7));
                float2 v1 = *(const float2*)(fb + ((size_t)e1.x << 7));
                float2 v2 = *(const float2*)(fb + ((size_t)e2.x << 7));
                float2 v3 = *(const float2*)(fb + ((size_t)e3.x << 7));
                float2 v4 = *(const float2*)(fb + ((size_t)e4.x << 7));
                float2 v5 = *(const float2*)(fb + ((size_t)e5.x << 7));
                float n0 = __int_as_float(e0.y), n1 = __int_as_float(e1.y);
                float n2 = __int_as_float(e2.y), n3 = __int_as_float(e3.y);
                float n4 = __int_as_float(e4.y), n5 = __int_as_float(e5.y);
                acc.x += n0 * v0.x + n1 * v1.x + n2 * v2.x
                       + n3 * v3.x + n4 * v4.x + n5 * v5.x;
                acc.y += n0 * v0.y + n1 * v1.y + n2 * v2.y
                       + n3 * v3.y + n4 * v4.y + n5 * v5.y;
                sn += n0 + n1 + n2 + n3 + n4 + n5;
            }
            for (; j + 2 <= end; j += 2) {
                int2 e0 = esn[j], e1 = esn[j + 1];
                const float* fb = featS + lane * 2;
                float2 v0 = *(const float2*)(fb + ((size_t)e0.x << 7));
                float2 v1 = *(const float2*)(fb + ((size_t)e1.x << 7));
                float n0 = __int_as_float(e0.y), n1 = __int_as_float(e1.y);
                acc.x += n0 * v0.x + n1 * v1.x;
                acc.y += n0 * v0.y + n1 * v1.y;
                sn += n0 + n1;
            }
            if (j < end) {
                int2 e0 = esn[j];
                float n0 = __int_as_float(e0.y);
                float2 v0 = *(const float2*)(featS + ((size_t)e0.x << 7) + lane * 2);
                acc.x += n0 * v0.x;
                acc.y += n0 * v0.y;
                sn += n0;
            }
        }
        float x0 = f2.x + acc.x, x1 = f2.y + acc.y;
        float y0 = f2.x * acc.x, y1 = f2.y * acc.y;
        unsigned int xh, xl, yh, yl;
        split2(x0, x1, xh, xl);
        split2(y0, y1, yh, yl);
        int swz = (r & 7) << 4;
        int rb = r * 512;
        int xo = rb + ((4 * lane) ^ swz);
        int yo = rb + ((256 + 4 * lane) ^ swz);
        *(unsigned int*)(pAh + xo) = xh;
        *(unsigned int*)(pAl + xo) = xl;
        *(unsigned int*)(pAh + yo) = yh;
        *(unsigned int*)(pAl + yo) = yl;
        if (lane == 0) sst[r] = sn;
    }
    __syncthreads();

    // ---- Phase 2: MFMA over K=256 (8 k-steps of 32) ----
    int r16 = lane & 15, g = lane >> 4;
    f32x4 acc0 = {0.f,0.f,0.f,0.f}, acc1 = {0.f,0.f,0.f,0.f};
    const char* cAh = (const char*)pAh;
    const char* cAl = (const char*)pAl;
    int swzA = (r16 & 7) << 4;
    int ob0 = r16 * 512;

    #pragma unroll 2
    for (int ks = 0; ks < 8; ++ks) {
        int offx = (ks * 64 + g * 16) ^ swzA;
        short8 a0h = *(const short8*)(cAh + ob0 + offx);
        short8 a0l = *(const short8*)(cAl + ob0 + offx);
        int mat = ks >> 2, ksm = ks & 3;
        const unsigned short* ph = wfrag + (size_t)mat * 32768;
        const unsigned short* pl = ph + 16384;
        int bo0 = ((ksm * 8 + w * 2) * 64 + lane) * 8;
        int bo1 = bo0 + 512;
        short8 b0h = *(const short8*)(ph + bo0);
        short8 b0l = *(const short8*)(pl + bo0);
        short8 b1h = *(const short8*)(ph + bo1);
        short8 b1l = *(const short8*)(pl + bo1);
        acc0 = __builtin_amdgcn_mfma_f32_16x16x32_bf16(a0h, b0h, acc0, 0, 0, 0);
        acc0 = __builtin_amdgcn_mfma_f32_16x16x32_bf16(a0h, b0l, acc0, 0, 0, 0);
        acc0 = __builtin_amdgcn_mfma_f32_16x16x32_bf16(a0l, b0h, acc0, 0, 0, 0);
        acc1 = __builtin_amdgcn_mfma_f32_16x16x32_bf16(a0h, b1h, acc1, 0, 0, 0);
        acc1 = __builtin_amdgcn_mfma_f32_16x16x32_bf16(a0h, b1l, acc1, 0, 0, 0);
        acc1 = __builtin_amdgcn_mfma_f32_16x16x32_bf16(a0l, b1h, acc1, 0, 0, 0);
    }
    __syncthreads();

    // ---- Phase 3: h -> LDS (reuse smem as padded f32 buf), epilogue ----
    float* hbuf = (float*)smem;    // FR x HS f32 = 8.7 KB
    #pragma unroll
    for (int j = 0; j < 4; ++j) {
        int rA = g * 4 + j;
        hbuf[rA * HS + (w * 32 + r16)]      = acc0[j];
        hbuf[rA * HS + (w * 32 + 16 + r16)] = acc1[j];
    }
    __syncthreads();

    int c0 = t & 63, c1 = c0 + 64, rg = t >> 6;
    float b1c0 = b1[c0], b1c1 = b1[c1];
    float b2c0 = b2[c0], b2c1 = b2[c1];
    #pragma unroll
    for (int rr = 0; rr < 4; ++rr) {
        int lr = rg * 4 + rr;
        int row_ = row0 + lr;
        if (row_ < nrows) {
            float s = sst[lr];
            float h0 = hbuf[lr * HS + c0] + (1.0f + s) * b1c0 + s * b2c0;
            float h1 = hbuf[lr * HS + c1] + (1.0f + s) * b1c1 + s * b2c1;
            h0 = h0 >= 0.f ? h0 : 0.2f * h0;
            h1 = h1 >= 0.f ? h1 : 0.2f * h1;
            float loc = h0 * h0 + h1 * h1;
            #pragma unroll
            for (int m = 32; m >= 1; m >>= 1) loc += __shfl_xor(loc, m, 64);
            float inv = 1.0f / fmaxf(sqrtf(loc), 1e-12f);
            __builtin_nontemporal_store(h0 * inv, out + (size_t)row_ * DD + c0);
            __builtin_nontemporal_store(h1 * inv, out + (size_t)row_ * DD + c1);
        }
    }
}

// ---------------- fp32 finish (fallback) ----------------

__global__ __launch_bounds__(256) void finish_kernel(
    const float* __restrict__ feat,
    const float* agg,
    const float* __restrict__ ssum,
    const float* __restrict__ W1,
    const float* __restrict__ b1,
    const float* __restrict__ W2,
    const float* __restrict__ b2,
    float* out,
    int nrows)
{
    __shared__ float xs[32][DD];
    __shared__ float ys[32][DD];
    int row0 = blockIdx.x * 32;
    int tid = threadIdx.x;

    for (int i = tid; i < 32 * (DD / 4); i += 256) {
        int r = i >> 5;
        int c4 = (i & 31) * 4;
        int row = row0 + r;
        if (row < nrows) {
            float4 f = *(const float4*)(feat + (size_t)row * DD + c4);
            float4 a = *(const float4*)(agg  + (size_t)row * DD + c4);
            float4 x, y;
            x.x = f.x + a.x; x.y = f.y + a.y; x.z = f.z + a.z; x.w = f.w + a.w;
            y.x = f.x * a.x; y.y = f.y * a.y; y.z = f.z * a.z; y.w = f.w * a.w;
            *(float4*)&xs[r][c4] = x;
            *(float4*)&ys[r][c4] = y;
        }
    }
    __syncthreads();

    int c0 = tid & 63;
    int rg = tid >> 6;
    int c1 = c0 + 64;

    float acc[8][2] = {{0.f,0.f},{0.f,0.f},{0.f,0.f},{0.f,0.f},
                       {0.f,0.f},{0.f,0.f},{0.f,0.f},{0.f,0.f}};
    for (int k = 0; k < DD; k += 4) {
        float w1a[4], w1b[4], w2a[4], w2b[4];
        #pragma unroll
        for (int kk = 0; kk < 4; ++kk) {
            const float* wr1 = W1 + (size_t)(k + kk) * DD;
            const float* wr2 = W2 + (size_t)(k + kk) * DD;
            w1a[kk] = wr1[c0]; w1b[kk] = wr1[c1];
            w2a[kk] = wr2[c0]; w2b[kk] = wr2[c1];
        }
        #pragma unroll
        for (int r = 0; r < 8; ++r) {
            float4 xv = *(const float4*)&xs[rg * 8 + r][k];
            float4 yv = *(const float4*)&ys[rg * 8 + r][k];
            acc[r][0] += xv.x*w1a[0] + xv.y*w1a[1] + xv.z*w1a[2] + xv.w*w1a[3]
                       + yv.x*w2a[0] + yv.y*w2a[1] + yv.z*w2a[2] + yv.w*w2a[3];
            acc[r][1] += xv.x*w1b[0] + xv.y*w1b[1] + xv.z*w1b[2] + xv.w*w1b[3]
                       + yv.x*w2b[0] + yv.y*w2b[1] + yv.z*w2b[2] + yv.w*w2b[3];
        }
    }

    float b1c0 = b1[c0], b1c1 = b1[c1];
    float b2c0 = b2[c0], b2c1 = b2[c1];

    #pragma unroll
    for (int r = 0; r < 8; ++r) {
        int row = row0 + rg * 8 + r;
        if (row < nrows) {
            float s = ssum[row];
            float h0 = acc[r][0] + (1.0f + s) * b1c0 + s * b2c0;
            float h1 = acc[r][1] + (1.0f + s) * b1c1 + s * b2c1;
            h0 = h0 >= 0.f ? h0 : 0.2f * h0;
            h1 = h1 >= 0.f ? h1 : 0.2f * h1;
            float loc = h0 * h0 + h1 * h1;
            #pragma unroll
            for (int m = 32; m >= 1; m >>= 1) loc += __shfl_xor(loc, m, 64);
            float inv = 1.0f / fmaxf(sqrtf(loc), 1e-12f);
            out[(size_t)row * DD + c0] = h0 * inv;
            out[(size_t)row * DD + c1] = h1 * inv;
        }
    }
}

extern "C" void kernel_launch(void* const* d_in, const int* in_sizes, int n_in,
                              void* d_out, int out_size, void* d_ws, size_t ws_size,
                              hipStream_t stream) {
    const float* feat_user = (const float*)d_in[0];
    const float* feat_item = (const float*)d_in[1];
    const float* W1        = (const float*)d_in[2];
    const float* b1        = (const float*)d_in[3];
    const float* W2        = (const float*)d_in[4];
    const float* b2        = (const float*)d_in[5];
    const float* norm_u2i  = (const float*)d_in[6];
    const float* norm_i2u  = (const float*)d_in[7];
    const int* eus = (const int*)d_in[8];
    const int* eud = (const int*)d_in[9];
    const int* eis = (const int*)d_in[10];
    const int* eid = (const int*)d_in[11];

    int NU = in_sizes[0] / DD;
    int NI = in_sizes[1] / DD;
    int E1 = in_sizes[8];
    int E2 = in_sizes[10];
    float* out = (float*)d_out;

    int nb0 = (NI + SCAN_TILE - 1) / SCAN_TILE;
    int nb1 = (NU + SCAN_TILE - 1) / SCAN_TILE;
    int nbU = (NU + FR - 1) / FR;
    int nbI = (NI + FR - 1) / FR;

    size_t wfrag_bytes = 131072;   // 4 planes x 32 KB
    size_t need_pg   = wfrag_bytes + 64 /*align slack*/ +
                       ((size_t)3 * NU + 3 * NI + 2 * E1 + 2 * E2 + 2
                        + nb0 + nb1) * sizeof(int);

    if (ws_size >= need_pg && nb0 + nb1 <= 512) {
        // ---- Tier 1: cooperative preamble + fused gather/MFMA finish ----
        unsigned short* wfrag = (unsigned short*)d_ws;   // 128 KB
        int* cur_i = (int*)((char*)d_ws + wfrag_bytes);  // NI
        int* cur_u = cur_i + NI;            // NU (contiguous after cur_i)
        int* row_i = cur_u + NU;            // NI+1
        int* row_u = row_i + NI + 1;        // NU+1
        int* pend  = row_u + NU + 1;
        int2* esn1 = (int2*)(((uintptr_t)pend + 15) & ~(uintptr_t)15);  // E1
        int2* esn2 = esn1 + E1;             // E2
        int* bsum  = (int*)(esn2 + E2);     // nb0+nb1 raw tile sums

        void* args[] = {
            (void*)&eud, (void*)&eus, (void*)&norm_u2i, (void*)&E1,
            (void*)&eid, (void*)&eis, (void*)&norm_i2u, (void*)&E2,
            (void*)&cur_i, (void*)&cur_u, (void*)&row_i, (void*)&row_u,
            (void*)&esn1, (void*)&esn2, (void*)&bsum,
            (void*)&nb0, (void*)&nb1, (void*)&NI, (void*)&NU,
            (void*)&W1, (void*)&W2, (void*)&wfrag
        };
        hipLaunchCooperativeKernel((void*)prep_kernel,
                                   dim3(PREP_GRID), dim3(256),
                                   args, 0, stream);

        fused_kernel<<<nbU + nbI, 256, 0, stream>>>(
            feat_user, feat_item,
            row_u, esn2, NU, nbU,
            row_i, esn1, NI,
            wfrag, b1, b2, out);
    } else {
        // ---- Fallback: atomic scatter + fp32 finish ----
        float* agg_user = out;
        float* agg_item = out + (size_t)NU * DD;
        float* s_user = (float*)d_ws;
        float* s_item = s_user + NU;

        hipMemsetAsync(out, 0, (size_t)out_size * sizeof(float), stream);
        hipMemsetAsync(d_ws, 0, (size_t)(NU + NI) * sizeof(float), stream);

        int b1n = (int)(((long long)E1 * 64 + 255) / 256);
        scatter_kernel<<<b1n, 256, 0, stream>>>(feat_user, eus, eud, norm_u2i,
                                                agg_item, s_item, E1);
        int b2n = (int)(((long long)E2 * 64 + 255) / 256);
        scatter_kernel<<<b2n, 256, 0, stream>>>(feat_item, eis, eid, norm_i2u,
                                                agg_user, s_user, E2);

        finish_kernel<<<(NU + 31) / 32, 256, 0, stream>>>(
            feat_user, agg_user, s_user, W1, b1, W2, b2, out, NU);
        finish_kernel<<<(NI + 31) / 32, 256, 0, stream>>>(
            feat_item, agg_item, s_item, W1, b1, W2, b2,
            out + (size_t)NU * DD, NI);
    }
}